// Round 1
// baseline (1649.102 us; speedup 1.0000x reference)
//
#include <hip/hip_runtime.h>
#include <math.h>

#define DD 128
#define NPB 98   // nodes per gemm block: grid = ceil(50000/98) = 511 <= 512 co-resident

__device__ __forceinline__ float wave_sum_f(float x) {
#pragma unroll
  for (int m = 32; m >= 1; m >>= 1) x += __shfl_xor(x, m, 64);
  return x;
}

__global__ void degrees_kernel(const int* __restrict__ src, const int* __restrict__ dst,
                               int* __restrict__ out_deg, int* __restrict__ in_deg, int E) {
  int e = blockIdx.x * blockDim.x + threadIdx.x;
  if (e < E) {
    atomicAdd(&out_deg[src[e]], 1);
    atomicAdd(&in_deg[dst[e]], 1);
  }
}

__global__ void norms_kernel(const int* __restrict__ in_deg, const int* __restrict__ out_deg,
                             float* __restrict__ norm_in, float* __restrict__ norm_out,
                             float* __restrict__ inv_in, int N) {
  int i = blockIdx.x * blockDim.x + threadIdx.x;
  if (i < N) {
    int di = in_deg[i], dq = out_deg[i];
    norm_in[i]  = di > 0 ? 1.0f / sqrtf((float)di) : 0.0f;
    norm_out[i] = dq > 0 ? 1.0f / sqrtf((float)dq) : 0.0f;
    inv_in[i]   = di > 0 ? 1.0f / (float)di : 0.0f;
  }
}

// single-block exclusive scan of in_deg -> row_off[N+1]
__global__ void scan_kernel(const int* __restrict__ deg, int* __restrict__ row_off, int N) {
  __shared__ int wsum[16];
  __shared__ int sbase;
  int t = threadIdx.x, lane = t & 63, wid = t >> 6;
  if (t == 0) sbase = 0;
  __syncthreads();
  for (int start = 0; start < N; start += 1024) {
    int i = start + t;
    int x = (i < N) ? deg[i] : 0;
    int v = x;
#pragma unroll
    for (int off = 1; off < 64; off <<= 1) {
      int y = __shfl_up(v, off, 64);
      if (lane >= off) v += y;
    }
    if (lane == 63) wsum[wid] = v;
    __syncthreads();
    int wbase = 0;
    for (int w = 0; w < wid; ++w) wbase += wsum[w];
    int incl = sbase + wbase + v;
    if (i < N) row_off[i] = incl - x;   // exclusive
    __syncthreads();
    if (t == 1023) sbase = incl;        // grand total so far (x=0 pads are harmless)
    __syncthreads();
  }
  if (t == 0) row_off[N] = sbase;
}

__global__ void csr_fill_kernel(const int* __restrict__ src, const int* __restrict__ dst,
                                const int* __restrict__ row_off, int* __restrict__ cursor,
                                int* __restrict__ csr_src, int E) {
  int e = blockIdx.x * blockDim.x + threadIdx.x;
  if (e < E) {
    int d = dst[e];
    int pos = row_off[d] + atomicAdd(&cursor[d], 1);
    csr_src[pos] = src[e];
  }
}

// Euclidean aggregation: out[v] = (sum_{s in N_in(v)} x[s]*norm_out[s]) * norm_in[v]
__global__ void agg_euclid_kernel(const float* __restrict__ x, const int* __restrict__ row_off,
                                  const int* __restrict__ csr_src, const float* __restrict__ norm_out,
                                  const float* __restrict__ norm_in, float* __restrict__ out) {
  int v = blockIdx.x, d = threadIdx.x;
  int beg = row_off[v], end = row_off[v + 1];
  float acc = 0.f;
  for (int i = beg; i < end; ++i) {
    int s = csr_src[i];
    acc += x[(size_t)s * DD + d] * norm_out[s];
  }
  out[(size_t)v * DD + d] = acc * norm_in[v];
}

// mean aggregation + expmap0 (SPHERE=0) or l2norm (SPHERE=1)
template <int SPHERE>
__global__ void agg_mean_map_kernel(const float* __restrict__ x, const int* __restrict__ row_off,
                                    const int* __restrict__ csr_src, const float* __restrict__ inv_in,
                                    float* __restrict__ out) {
  __shared__ float red[2];
  int v = blockIdx.x, d = threadIdx.x;
  int beg = row_off[v], end = row_off[v + 1];
  float acc = 0.f;
  for (int i = beg; i < end; ++i) acc += x[(size_t)csr_src[i] * DD + d];
  float u = acc * inv_in[v];
  float ps = wave_sum_f(u * u);
  if ((d & 63) == 0) red[d >> 6] = ps;
  __syncthreads();
  float n = sqrtf(red[0] + red[1]);
  float f;
  if (SPHERE) f = 1.0f / fmaxf(n, 1e-12f);
  else        f = tanhf(n) / fmaxf(n, 1e-7f);  // expmap0
  out[(size_t)v * DD + d] = u * f;
}

// out = act( pre(in) @ W^T + B ).  MODE 0: identity-in + leaky_relu(0.2)
//                                  MODE 1: logmap0-in, no act
//                                  MODE 2: l2norm-in, no act
// W (128x128) staged in LDS with XOR swizzle: W[d][k] at d*128 + (k ^ (d&31))
// -> conflict-free staging writes AND conflict-free per-k reads.
template <int MODE>
__global__ __launch_bounds__(256) void gemm_kernel(const float* __restrict__ in,
                                                   const float* __restrict__ W,
                                                   const float* __restrict__ B,
                                                   float* __restrict__ out, int N) {
  __shared__ float Wl[DD * DD];
  int t = threadIdx.x;
#pragma unroll
  for (int i = 0; i < (DD * DD) / 256; ++i) {
    int g = t + i * 256;
    Wl[g ^ ((g >> 7) & 31)] = W[g];
  }
  __syncthreads();
  int lane = t & 63, wid = t >> 6;
  float b0 = B[lane], b1 = B[lane + 64];
  int dbase = lane * DD;
  int dbase2 = dbase + 64 * DD;  // (lane+64)*DD, same xor key since (lane+64)&31 == lane&31
  int dx = lane & 31;
  int vend = (blockIdx.x + 1) * NPB; if (vend > N) vend = N;
  for (int v = blockIdx.x * NPB + wid; v < vend; v += 4) {
    float r0 = in[(size_t)v * DD + lane];
    float r1 = in[(size_t)v * DD + 64 + lane];
    if (MODE != 0) {
      float nsq = wave_sum_f(r0 * r0 + r1 * r1);  // full 128-dim norm in one wave
      float n = sqrtf(nsq);
      float f;
      if (MODE == 1) {
        float nc = fminf(fmaxf(n, 1e-7f), 1.0f - 1e-5f);
        f = atanhf(nc) / fmaxf(n, 1e-7f);
      } else {
        f = 1.0f / fmaxf(n, 1e-12f);
      }
      r0 *= f; r1 *= f;
    }
    float acc0 = b0, acc1 = b1;
#pragma unroll 8
    for (int k = 0; k < 64; ++k) {
      float a = __shfl(r0, k, 64);
      int kx = k ^ dx;
      acc0 += a * Wl[dbase + kx];
      acc1 += a * Wl[dbase2 + kx];
    }
#pragma unroll 8
    for (int k = 64; k < 128; ++k) {
      float a = __shfl(r1, k - 64, 64);
      int kx = k ^ dx;
      acc0 += a * Wl[dbase + kx];
      acc1 += a * Wl[dbase2 + kx];
    }
    if (MODE == 0) {
      acc0 = acc0 > 0.f ? acc0 : 0.2f * acc0;
      acc1 = acc1 > 0.f ? acc1 : 0.2f * acc1;
    }
    out[(size_t)v * DD + lane] = acc0;
    out[(size_t)v * DD + 64 + lane] = acc1;
  }
}

extern "C" void kernel_launch(void* const* d_in, const int* in_sizes, int n_in,
                              void* d_out, int out_size, void* d_ws, size_t ws_size,
                              hipStream_t stream) {
  const float* e0 = (const float*)d_in[0];
  const float* b0 = (const float*)d_in[1];
  const float* s0 = (const float*)d_in[2];
  const float* eW = (const float*)d_in[3];
  const float* eB = (const float*)d_in[4];
  const float* bW = (const float*)d_in[5];
  const float* bB = (const float*)d_in[6];
  const float* sW = (const float*)d_in[7];
  const float* sB = (const float*)d_in[8];
  const int* src = (const int*)d_in[9];
  const int* dst = (const int*)d_in[10];
  int N = in_sizes[0] / DD;
  int E = in_sizes[9];
  int L = in_sizes[3] / (DD * DD);

  char* w = (char*)d_ws;
  int* in_deg  = (int*)w; w += (size_t)N * 4;
  int* out_deg = (int*)w; w += (size_t)N * 4;
  int* cursor  = (int*)w; w += (size_t)N * 4;
  int* row_off = (int*)w; w += (size_t)(N + 4) * 4;
  int* csr_src = (int*)w; w += (size_t)E * 4;
  float* norm_in  = (float*)w; w += (size_t)N * 4;
  float* norm_out = (float*)w; w += (size_t)N * 4;
  float* inv_in   = (float*)w; w += (size_t)N * 4;
  float* buf_agg  = (float*)w; w += (size_t)N * DD * 4;
  float* buf_tan  = (float*)w; w += (size_t)N * DD * 4;

  float* oe = (float*)d_out;
  float* ob = oe + (size_t)N * DD;
  float* os = ob + (size_t)N * DD;

  // zero in_deg, out_deg, cursor (contiguous)
  hipMemsetAsync(d_ws, 0, (size_t)3 * N * 4, stream);
  degrees_kernel<<<(E + 255) / 256, 256, 0, stream>>>(src, dst, out_deg, in_deg, E);
  norms_kernel<<<(N + 255) / 256, 256, 0, stream>>>(in_deg, out_deg, norm_in, norm_out, inv_in, N);
  scan_kernel<<<1, 1024, 0, stream>>>(in_deg, row_off, N);
  csr_fill_kernel<<<(E + 255) / 256, 256, 0, stream>>>(src, dst, row_off, cursor, csr_src, E);

  const float* ec = e0; const float* bc = b0; const float* scur = s0;
  int gblocks = (N + NPB - 1) / NPB;
  for (int l = 0; l < L; ++l) {
    // Euclidean: agg (reads ec) then GEMM -> oe (safe to alias ec)
    agg_euclid_kernel<<<N, DD, 0, stream>>>(ec, row_off, csr_src, norm_out, norm_in, buf_agg);
    gemm_kernel<0><<<gblocks, 256, 0, stream>>>(buf_agg, eW + (size_t)l * DD * DD, eB + (size_t)l * DD, oe, N);
    // Hyperbolic: logmap+GEMM (reads bc) -> buf_tan, then mean-agg+expmap -> ob
    gemm_kernel<1><<<gblocks, 256, 0, stream>>>(bc, bW + (size_t)l * DD * DD, bB + (size_t)l * DD, buf_tan, N);
    agg_mean_map_kernel<0><<<N, DD, 0, stream>>>(buf_tan, row_off, csr_src, inv_in, ob);
    // Spherical: l2norm+GEMM (reads scur) -> buf_tan, then mean-agg+l2norm -> os
    gemm_kernel<2><<<gblocks, 256, 0, stream>>>(scur, sW + (size_t)l * DD * DD, sB + (size_t)l * DD, buf_tan, N);
    agg_mean_map_kernel<1><<<N, DD, 0, stream>>>(buf_tan, row_off, csr_src, inv_in, os);
    ec = oe; bc = ob; scur = os;
  }
}

// Round 2
// 1449.311 us; speedup vs baseline: 1.1379x; 1.1379x over previous
//
#include <hip/hip_runtime.h>
#include <math.h>

#define DD 128

__device__ __forceinline__ float wave_sum_f(float x) {
#pragma unroll
  for (int m = 32; m >= 1; m >>= 1) x += __shfl_xor(x, m, 64);
  return x;
}
__device__ __forceinline__ int wave_sum_i(int x) {
#pragma unroll
  for (int m = 32; m >= 1; m >>= 1) x += __shfl_xor(x, m, 64);
  return x;
}

__global__ void degrees_kernel(const int* __restrict__ src, const int* __restrict__ dst,
                               int* __restrict__ out_deg, int* __restrict__ in_deg, int E) {
  int e = blockIdx.x * blockDim.x + threadIdx.x;
  if (e < E) {
    atomicAdd(&out_deg[src[e]], 1);
    atomicAdd(&in_deg[dst[e]], 1);
  }
}

__global__ void norms_kernel(const int* __restrict__ in_deg, const int* __restrict__ out_deg,
                             float* __restrict__ norm_in, float* __restrict__ norm_out,
                             float* __restrict__ inv_in, int N) {
  int i = blockIdx.x * blockDim.x + threadIdx.x;
  if (i < N) {
    int di = in_deg[i], dq = out_deg[i];
    norm_in[i]  = di > 0 ? 1.0f / sqrtf((float)di) : 0.0f;
    norm_out[i] = dq > 0 ? 1.0f / sqrtf((float)dq) : 0.0f;
    inv_in[i]   = di > 0 ? 1.0f / (float)di : 0.0f;
  }
}

// ---- 3-phase scan of in_deg -> row_off (exclusive) ----
__global__ void part_sum_kernel(const int* __restrict__ deg, int* __restrict__ part, int N) {
  __shared__ int wsum[4];
  int t = threadIdx.x, lane = t & 63, w = t >> 6;
  int i = blockIdx.x * 256 + t;
  int x = (i < N) ? deg[i] : 0;
  int s = wave_sum_i(x);
  if (lane == 0) wsum[w] = s;
  __syncthreads();
  if (t == 0) part[blockIdx.x] = wsum[0] + wsum[1] + wsum[2] + wsum[3];
}

__global__ void part_scan_kernel(int* __restrict__ part, int nb) {
  __shared__ int wsum[4];
  int t = threadIdx.x, lane = t & 63, w = t >> 6;
  int x = (t < nb) ? part[t] : 0;
  int v = x;
#pragma unroll
  for (int off = 1; off < 64; off <<= 1) {
    int y = __shfl_up(v, off, 64);
    if (lane >= off) v += y;
  }
  if (lane == 63) wsum[w] = v;
  __syncthreads();
  int base = 0;
  for (int q = 0; q < w; ++q) base += wsum[q];
  if (t < nb) part[t] = base + v - x;  // exclusive
}

__global__ void local_scan_kernel(const int* __restrict__ deg, const int* __restrict__ part,
                                  int* __restrict__ row_off, int N, int E) {
  __shared__ int wsum[4];
  int t = threadIdx.x, lane = t & 63, w = t >> 6;
  int i = blockIdx.x * 256 + t;
  int x = (i < N) ? deg[i] : 0;
  int v = x;
#pragma unroll
  for (int off = 1; off < 64; off <<= 1) {
    int y = __shfl_up(v, off, 64);
    if (lane >= off) v += y;
  }
  if (lane == 63) wsum[w] = v;
  __syncthreads();
  int base = 0;
  for (int q = 0; q < w; ++q) base += wsum[q];
  if (i < N) row_off[i] = part[blockIdx.x] + base + v - x;
  if (blockIdx.x == 0 && t == 0) row_off[N] = E;
}

__global__ void csr_fill_kernel(const int* __restrict__ src, const int* __restrict__ dst,
                                const int* __restrict__ row_off, int* __restrict__ cursor,
                                int* __restrict__ csr_src, int E) {
  int e = blockIdx.x * blockDim.x + threadIdx.x;
  if (e < E) {
    int d = dst[e];
    int pos = row_off[d] + atomicAdd(&cursor[d], 1);
    csr_src[pos] = src[e];
  }
}

// per-row pre-transform scalar: MODE 1 = logmap0 (atanh(clip(n))/max(n,1e-7))
//                               MODE 2 = l2norm  (1/max(n,1e-12))
template <int MODE>
__global__ void scale_kernel(const float* __restrict__ x, float* __restrict__ s, int N) {
  int lane = threadIdx.x & 63;
  int v = blockIdx.x * 4 + (threadIdx.x >> 6);
  if (v >= N) return;
  float2 a = ((const float2*)x)[(size_t)v * 64 + lane];
  float n = sqrtf(wave_sum_f(a.x * a.x + a.y * a.y));
  float f;
  if (MODE == 1) {
    float nc = fminf(fmaxf(n, 1e-7f), 1.0f - 1e-5f);
    f = atanhf(nc) / fmaxf(n, 1e-7f);
  } else {
    f = 1.0f / fmaxf(n, 1e-12f);
  }
  if (lane == 0) s[v] = f;
}

// Euclidean agg: out[v] = norm_in[v] * sum_{s in N_in(v)} x[s]*norm_out[s]
__global__ void agg_euclid_kernel(const float* __restrict__ x, const int* __restrict__ row_off,
                                  const int* __restrict__ csr_src, const float* __restrict__ norm_out,
                                  const float* __restrict__ norm_in, float* __restrict__ out, int N) {
  int lane = threadIdx.x & 63;
  int v = blockIdx.x * 4 + (threadIdx.x >> 6);
  if (v >= N) return;
  const float2* x2 = (const float2*)x;
  int beg = row_off[v], end = row_off[v + 1];
  float ax0 = 0.f, ay0 = 0.f, ax1 = 0.f, ay1 = 0.f;
  int i = beg;
  for (; i + 2 <= end; i += 2) {
    int sA = csr_src[i], sB = csr_src[i + 1];
    float2 xA = x2[(size_t)sA * 64 + lane];
    float2 xB = x2[(size_t)sB * 64 + lane];
    float wA = norm_out[sA], wB = norm_out[sB];
    ax0 += xA.x * wA; ay0 += xA.y * wA;
    ax1 += xB.x * wB; ay1 += xB.y * wB;
  }
  if (i < end) {
    int sA = csr_src[i];
    float2 xA = x2[(size_t)sA * 64 + lane];
    float wA = norm_out[sA];
    ax0 += xA.x * wA; ay0 += xA.y * wA;
  }
  float ni = norm_in[v];
  float2 o; o.x = (ax0 + ax1) * ni; o.y = (ay0 + ay1) * ni;
  ((float2*)out)[(size_t)v * 64 + lane] = o;
}

// mean agg + expmap0 (SPHERE=0) or l2norm (SPHERE=1); also emits next-layer
// pre-transform scalar snext[v] from the post-map norm.
template <int SPHERE>
__global__ void agg_mean_map_kernel(const float* __restrict__ x, const int* __restrict__ row_off,
                                    const int* __restrict__ csr_src, const float* __restrict__ inv_in,
                                    float* __restrict__ out, float* __restrict__ snext, int N) {
  int lane = threadIdx.x & 63;
  int v = blockIdx.x * 4 + (threadIdx.x >> 6);
  if (v >= N) return;
  const float2* x2 = (const float2*)x;
  int beg = row_off[v], end = row_off[v + 1];
  float ax0 = 0.f, ay0 = 0.f, ax1 = 0.f, ay1 = 0.f;
  int i = beg;
  for (; i + 2 <= end; i += 2) {
    int sA = csr_src[i], sB = csr_src[i + 1];
    float2 xA = x2[(size_t)sA * 64 + lane];
    float2 xB = x2[(size_t)sB * 64 + lane];
    ax0 += xA.x; ay0 += xA.y;
    ax1 += xB.x; ay1 += xB.y;
  }
  if (i < end) {
    int sA = csr_src[i];
    float2 xA = x2[(size_t)sA * 64 + lane];
    ax0 += xA.x; ay0 += xA.y;
  }
  float iv = inv_in[v];
  float ux = (ax0 + ax1) * iv, uy = (ay0 + ay1) * iv;
  float n = sqrtf(wave_sum_f(ux * ux + uy * uy));
  float f;
  if (SPHERE) f = 1.0f / fmaxf(n, 1e-12f);
  else        f = tanhf(n) / fmaxf(n, 1e-7f);  // expmap0
  float2 o; o.x = ux * f; o.y = uy * f;
  ((float2*)out)[(size_t)v * 64 + lane] = o;
  if (lane == 0) {
    float m = f * n;  // norm of the mapped row
    float s2;
    if (SPHERE) s2 = 1.0f / fmaxf(m, 1e-12f);
    else {
      float nc = fminf(fmaxf(m, 1e-7f), 1.0f - 1e-5f);
      s2 = atanhf(nc) / fmaxf(m, 1e-7f);
    }
    snext[v] = s2;
  }
}

// out = act( s[v] * (in @ W^T) + B ).  MODE 0: s=1, leaky_relu(0.2); MODE 1/2: s from scale[], no act.
// W quadrant per wave in VGPRs: wave (c,h) holds W[64c+lane][64h:64h+64] (64 regs/lane).
// A-row read as wave-uniform float4 broadcast loads; k-half partials combined via 8KB LDS.
template <int MODE>
__global__ __launch_bounds__(256) void gemm_rw_kernel(const float* __restrict__ in,
                                                      const float* __restrict__ W,
                                                      const float* __restrict__ Bb,
                                                      const float* __restrict__ scale,
                                                      float* __restrict__ out, int N) {
  __shared__ float lds[16 * DD];
  int t = threadIdx.x, lane = t & 63, w = t >> 6;
  int c = w & 1, h = w >> 1;
  int col = c * 64 + lane;
  // W quadrant -> registers
  const float4* Wp4 = (const float4*)(W + (size_t)col * DD + h * 64);
  float4 wv[16];
#pragma unroll
  for (int q = 0; q < 16; ++q) wv[q] = Wp4[q];
  float bias = Bb[col];
  int r0base = blockIdx.x * 64;

  for (int it = 0; it < 4; ++it) {
    int rbase = r0base + it * 16;
    float acc[16];
#pragma unroll
    for (int r = 0; r < 16; ++r) acc[r] = 0.f;
#pragma unroll
    for (int r = 0; r < 16; ++r) {
      int v = rbase + r;
      if (v < N) {
        const float4* Ar = (const float4*)(in + (size_t)v * DD + h * 64);
        float p0 = 0.f, p1 = 0.f, p2 = 0.f, p3 = 0.f;
#pragma unroll
        for (int q = 0; q < 16; q += 4) {
          float4 a0 = Ar[q], a1 = Ar[q + 1], a2 = Ar[q + 2], a3 = Ar[q + 3];
          p0 += a0.x * wv[q].x     + a0.y * wv[q].y     + a0.z * wv[q].z     + a0.w * wv[q].w;
          p1 += a1.x * wv[q + 1].x + a1.y * wv[q + 1].y + a1.z * wv[q + 1].z + a1.w * wv[q + 1].w;
          p2 += a2.x * wv[q + 2].x + a2.y * wv[q + 2].y + a2.z * wv[q + 2].z + a2.w * wv[q + 2].w;
          p3 += a3.x * wv[q + 3].x + a3.y * wv[q + 3].y + a3.z * wv[q + 3].z + a3.w * wv[q + 3].w;
        }
        acc[r] = (p0 + p1) + (p2 + p3);
      }
    }
    __syncthreads();  // protect LDS reuse from previous iteration
    // each wave parks the 8 rows its partner finalizes
    if (h == 0) {
#pragma unroll
      for (int r = 8; r < 16; ++r) lds[r * DD + col] = acc[r];
    } else {
#pragma unroll
      for (int r = 0; r < 8; ++r) lds[r * DD + col] = acc[r];
    }
    __syncthreads();
    if (h == 0) {
#pragma unroll
      for (int r = 0; r < 8; ++r) {
        int v = rbase + r;
        if (v < N) {
          float val = acc[r] + lds[r * DD + col];
          if (MODE == 0) { val += bias; val = val > 0.f ? val : 0.2f * val; }
          else           { val = val * scale[v] + bias; }
          out[(size_t)v * DD + col] = val;
        }
      }
    } else {
#pragma unroll
      for (int r = 8; r < 16; ++r) {
        int v = rbase + r;
        if (v < N) {
          float val = acc[r] + lds[r * DD + col];
          if (MODE == 0) { val += bias; val = val > 0.f ? val : 0.2f * val; }
          else           { val = val * scale[v] + bias; }
          out[(size_t)v * DD + col] = val;
        }
      }
    }
  }
}

extern "C" void kernel_launch(void* const* d_in, const int* in_sizes, int n_in,
                              void* d_out, int out_size, void* d_ws, size_t ws_size,
                              hipStream_t stream) {
  const float* e0 = (const float*)d_in[0];
  const float* b0 = (const float*)d_in[1];
  const float* s0 = (const float*)d_in[2];
  const float* eW = (const float*)d_in[3];
  const float* eB = (const float*)d_in[4];
  const float* bW = (const float*)d_in[5];
  const float* bB = (const float*)d_in[6];
  const float* sW = (const float*)d_in[7];
  const float* sB = (const float*)d_in[8];
  const int* src = (const int*)d_in[9];
  const int* dst = (const int*)d_in[10];
  int N = in_sizes[0] / DD;
  int E = in_sizes[9];
  int L = in_sizes[3] / (DD * DD);

  char* w = (char*)d_ws;
  int* in_deg  = (int*)w; w += (size_t)N * 4;
  int* out_deg = (int*)w; w += (size_t)N * 4;
  int* cursor  = (int*)w; w += (size_t)N * 4;
  int* row_off = (int*)w; w += (size_t)(N + 4) * 4;
  int* part    = (int*)w; w += (size_t)1024 * 4;
  int* csr_src = (int*)w; w += (size_t)E * 4;
  float* norm_in  = (float*)w; w += (size_t)N * 4;
  float* norm_out = (float*)w; w += (size_t)N * 4;
  float* inv_in   = (float*)w; w += (size_t)N * 4;
  float* sb       = (float*)w; w += (size_t)N * 4;
  float* ss       = (float*)w; w += (size_t)N * 4;
  float* buf_agg  = (float*)w; w += (size_t)N * DD * 4;
  float* buf_tan  = (float*)w; w += (size_t)N * DD * 4;

  float* oe = (float*)d_out;
  float* ob = oe + (size_t)N * DD;
  float* os = ob + (size_t)N * DD;

  int PB = (N + 255) / 256;      // scan blocks (196)
  int AB = (N + 3) / 4;          // wave-per-row blocks (12500)
  int GB = (N + 63) / 64;        // gemm blocks (782)

  hipMemsetAsync(d_ws, 0, (size_t)3 * N * 4, stream);  // in_deg,out_deg,cursor
  degrees_kernel<<<(E + 255) / 256, 256, 0, stream>>>(src, dst, out_deg, in_deg, E);
  norms_kernel<<<(N + 255) / 256, 256, 0, stream>>>(in_deg, out_deg, norm_in, norm_out, inv_in, N);
  part_sum_kernel<<<PB, 256, 0, stream>>>(in_deg, part, N);
  part_scan_kernel<<<1, 256, 0, stream>>>(part, PB);
  local_scan_kernel<<<PB, 256, 0, stream>>>(in_deg, part, row_off, N, E);
  csr_fill_kernel<<<(E + 255) / 256, 256, 0, stream>>>(src, dst, row_off, cursor, csr_src, E);
  scale_kernel<1><<<AB, 256, 0, stream>>>(b0, sb, N);
  scale_kernel<2><<<AB, 256, 0, stream>>>(s0, ss, N);

  const float* ec = e0; const float* bc = b0; const float* scur = s0;
  for (int l = 0; l < L; ++l) {
    // Euclidean: agg (reads ec) then GEMM -> oe
    agg_euclid_kernel<<<AB, 256, 0, stream>>>(ec, row_off, csr_src, norm_out, norm_in, buf_agg, N);
    gemm_rw_kernel<0><<<GB, 256, 0, stream>>>(buf_agg, eW + (size_t)l * DD * DD, eB + (size_t)l * DD, nullptr, oe, N);
    // Hyperbolic: (logmap0-scaled) GEMM -> buf_tan, then mean-agg + expmap0 -> ob (+ next scale)
    gemm_rw_kernel<1><<<GB, 256, 0, stream>>>(bc, bW + (size_t)l * DD * DD, bB + (size_t)l * DD, sb, buf_tan, N);
    agg_mean_map_kernel<0><<<AB, 256, 0, stream>>>(buf_tan, row_off, csr_src, inv_in, ob, sb, N);
    // Spherical: (l2norm-scaled) GEMM -> buf_tan, then mean-agg + l2norm -> os (+ next scale)
    gemm_rw_kernel<2><<<GB, 256, 0, stream>>>(scur, sW + (size_t)l * DD * DD, sB + (size_t)l * DD, ss, buf_tan, N);
    agg_mean_map_kernel<1><<<AB, 256, 0, stream>>>(buf_tan, row_off, csr_src, inv_in, os, ss, N);
    ec = oe; bc = ob; scur = os;
  }
}

// Round 3
// 858.073 us; speedup vs baseline: 1.9219x; 1.6890x over previous
//
#include <hip/hip_runtime.h>
#include <math.h>

#define DD 128

__device__ __forceinline__ float wave_sum_f(float x) {
#pragma unroll
  for (int m = 32; m >= 1; m >>= 1) x += __shfl_xor(x, m, 64);
  return x;
}
__device__ __forceinline__ int wave_sum_i(int x) {
#pragma unroll
  for (int m = 32; m >= 1; m >>= 1) x += __shfl_xor(x, m, 64);
  return x;
}

__global__ void degrees_kernel(const int* __restrict__ src, const int* __restrict__ dst,
                               int* __restrict__ out_deg, int* __restrict__ in_deg, int E) {
  int e = blockIdx.x * blockDim.x + threadIdx.x;
  if (e < E) {
    atomicAdd(&out_deg[src[e]], 1);
    atomicAdd(&in_deg[dst[e]], 1);
  }
}

__global__ void norms_kernel(const int* __restrict__ in_deg, const int* __restrict__ out_deg,
                             float* __restrict__ norm_in, float* __restrict__ norm_out,
                             float* __restrict__ inv_in, int N) {
  int i = blockIdx.x * blockDim.x + threadIdx.x;
  if (i < N) {
    int di = in_deg[i], dq = out_deg[i];
    norm_in[i]  = di > 0 ? 1.0f / sqrtf((float)di) : 0.0f;
    norm_out[i] = dq > 0 ? 1.0f / sqrtf((float)dq) : 0.0f;
    inv_in[i]   = di > 0 ? 1.0f / (float)di : 0.0f;
  }
}

// ---- 3-phase scan of in_deg -> row_off (exclusive) ----
__global__ void part_sum_kernel(const int* __restrict__ deg, int* __restrict__ part, int N) {
  __shared__ int wsum[4];
  int t = threadIdx.x, lane = t & 63, w = t >> 6;
  int i = blockIdx.x * 256 + t;
  int x = (i < N) ? deg[i] : 0;
  int s = wave_sum_i(x);
  if (lane == 0) wsum[w] = s;
  __syncthreads();
  if (t == 0) part[blockIdx.x] = wsum[0] + wsum[1] + wsum[2] + wsum[3];
}

__global__ void part_scan_kernel(int* __restrict__ part, int nb) {
  __shared__ int wsum[4];
  int t = threadIdx.x, lane = t & 63, w = t >> 6;
  int x = (t < nb) ? part[t] : 0;
  int v = x;
#pragma unroll
  for (int off = 1; off < 64; off <<= 1) {
    int y = __shfl_up(v, off, 64);
    if (lane >= off) v += y;
  }
  if (lane == 63) wsum[w] = v;
  __syncthreads();
  int base = 0;
  for (int q = 0; q < w; ++q) base += wsum[q];
  if (t < nb) part[t] = base + v - x;  // exclusive
}

__global__ void local_scan_kernel(const int* __restrict__ deg, const int* __restrict__ part,
                                  int* __restrict__ row_off, int N, int E) {
  __shared__ int wsum[4];
  int t = threadIdx.x, lane = t & 63, w = t >> 6;
  int i = blockIdx.x * 256 + t;
  int x = (i < N) ? deg[i] : 0;
  int v = x;
#pragma unroll
  for (int off = 1; off < 64; off <<= 1) {
    int y = __shfl_up(v, off, 64);
    if (lane >= off) v += y;
  }
  if (lane == 63) wsum[w] = v;
  __syncthreads();
  int base = 0;
  for (int q = 0; q < w; ++q) base += wsum[q];
  if (i < N) row_off[i] = part[blockIdx.x] + base + v - x;
  if (blockIdx.x == 0 && t == 0) row_off[N] = E;
}

__global__ void csr_fill_kernel(const int* __restrict__ src, const int* __restrict__ dst,
                                const int* __restrict__ row_off, int* __restrict__ cursor,
                                int* __restrict__ csr_src, int E) {
  int e = blockIdx.x * blockDim.x + threadIdx.x;
  if (e < E) {
    int d = dst[e];
    int pos = row_off[d] + atomicAdd(&cursor[d], 1);
    csr_src[pos] = src[e];
  }
}

// per-row pre-transform scalar: MODE 1 = logmap0 (atanh(clip(n))/max(n,1e-7))
//                               MODE 2 = l2norm  (1/max(n,1e-12))
template <int MODE>
__global__ void scale_kernel(const float* __restrict__ x, float* __restrict__ s, int N) {
  int lane = threadIdx.x & 63;
  int v = blockIdx.x * 4 + (threadIdx.x >> 6);
  if (v >= N) return;
  float2 a = ((const float2*)x)[(size_t)v * 64 + lane];
  float n = sqrtf(wave_sum_f(a.x * a.x + a.y * a.y));
  float f;
  if (MODE == 1) {
    float nc = fminf(fmaxf(n, 1e-7f), 1.0f - 1e-5f);
    f = atanhf(nc) / fmaxf(n, 1e-7f);
  } else {
    f = 1.0f / fmaxf(n, 1e-12f);
  }
  if (lane == 0) s[v] = f;
}

// Euclidean agg: out[v] = norm_in[v] * sum_{s in N_in(v)} x[s]*norm_out[s]
__global__ void agg_euclid_kernel(const float* __restrict__ x, const int* __restrict__ row_off,
                                  const int* __restrict__ csr_src, const float* __restrict__ norm_out,
                                  const float* __restrict__ norm_in, float* __restrict__ out, int N) {
  int lane = threadIdx.x & 63;
  int v = blockIdx.x * 4 + (threadIdx.x >> 6);
  if (v >= N) return;
  const float2* x2 = (const float2*)x;
  int beg = row_off[v], end = row_off[v + 1];
  float ax0 = 0.f, ay0 = 0.f, ax1 = 0.f, ay1 = 0.f;
  int i = beg;
  for (; i + 2 <= end; i += 2) {
    int sA = csr_src[i], sB = csr_src[i + 1];
    float2 xA = x2[(size_t)sA * 64 + lane];
    float2 xB = x2[(size_t)sB * 64 + lane];
    float wA = norm_out[sA], wB = norm_out[sB];
    ax0 += xA.x * wA; ay0 += xA.y * wA;
    ax1 += xB.x * wB; ay1 += xB.y * wB;
  }
  if (i < end) {
    int sA = csr_src[i];
    float2 xA = x2[(size_t)sA * 64 + lane];
    float wA = norm_out[sA];
    ax0 += xA.x * wA; ay0 += xA.y * wA;
  }
  float ni = norm_in[v];
  float2 o; o.x = (ax0 + ax1) * ni; o.y = (ay0 + ay1) * ni;
  ((float2*)out)[(size_t)v * 64 + lane] = o;
}

// mean agg + expmap0 (SPHERE=0) or l2norm (SPHERE=1); also emits next-layer
// pre-transform scalar snext[v] from the post-map norm.
template <int SPHERE>
__global__ void agg_mean_map_kernel(const float* __restrict__ x, const int* __restrict__ row_off,
                                    const int* __restrict__ csr_src, const float* __restrict__ inv_in,
                                    float* __restrict__ out, float* __restrict__ snext, int N) {
  int lane = threadIdx.x & 63;
  int v = blockIdx.x * 4 + (threadIdx.x >> 6);
  if (v >= N) return;
  const float2* x2 = (const float2*)x;
  int beg = row_off[v], end = row_off[v + 1];
  float ax0 = 0.f, ay0 = 0.f, ax1 = 0.f, ay1 = 0.f;
  int i = beg;
  for (; i + 2 <= end; i += 2) {
    int sA = csr_src[i], sB = csr_src[i + 1];
    float2 xA = x2[(size_t)sA * 64 + lane];
    float2 xB = x2[(size_t)sB * 64 + lane];
    ax0 += xA.x; ay0 += xA.y;
    ax1 += xB.x; ay1 += xB.y;
  }
  if (i < end) {
    int sA = csr_src[i];
    float2 xA = x2[(size_t)sA * 64 + lane];
    ax0 += xA.x; ay0 += xA.y;
  }
  float iv = inv_in[v];
  float ux = (ax0 + ax1) * iv, uy = (ay0 + ay1) * iv;
  float n = sqrtf(wave_sum_f(ux * ux + uy * uy));
  float f;
  if (SPHERE) f = 1.0f / fmaxf(n, 1e-12f);
  else        f = tanhf(n) / fmaxf(n, 1e-7f);  // expmap0
  float2 o; o.x = ux * f; o.y = uy * f;
  ((float2*)out)[(size_t)v * 64 + lane] = o;
  if (lane == 0) {
    float m = f * n;  // norm of the mapped row
    float s2;
    if (SPHERE) s2 = 1.0f / fmaxf(m, 1e-12f);
    else {
      float nc = fminf(fmaxf(m, 1e-7f), 1.0f - 1e-5f);
      s2 = atanhf(nc) / fmaxf(m, 1e-7f);
    }
    snext[v] = s2;
  }
}

// Classic LDS rank-1 SGEMM: out[v][c] = post( s[v]*(in[v][:] . W[c][:]) + B[c] )
// BM=64 rows, BN=128 cols (full), BK=32. 256 threads, thread tile 4x8.
// A staged transposed As[k][r] (pad 68), W staged transposed Ws[k][c] (pad 132).
// MODE 0: s=1, leaky_relu(0.2). MODE 1/2: s=scale[v], no act.
template <int MODE>
__global__ __launch_bounds__(256, 4) void gemm_tile_kernel(const float* __restrict__ in,
                                                           const float* __restrict__ W,
                                                           const float* __restrict__ Bb,
                                                           const float* __restrict__ scale,
                                                           float* __restrict__ out, int N) {
  __shared__ float As[32][68];
  __shared__ float Ws[32][132];
  int t = threadIdx.x;
  int tx = t & 15, ty = t >> 4;       // tx: col octet, ty: row quartet
  int rbase = blockIdx.x * 64;

  float acc[4][8];
#pragma unroll
  for (int i = 0; i < 4; ++i)
#pragma unroll
    for (int j = 0; j < 8; ++j) acc[i][j] = 0.f;

  int sr = t & 63, skq = t >> 6;       // A staging: row, k-octet (4 octets of 8)
  int sc = t & 127, skh = t >> 7;      // W staging: col, k-half (2 halves of 16)
  int vclamp = rbase + sr; if (vclamp >= N) vclamp = N - 1;
  const float* Arow = in + (size_t)vclamp * DD;
  const float* Wrow = W + (size_t)sc * DD;

  for (int kc = 0; kc < 4; ++kc) {
    int k0 = kc * 32;
    // ---- stage A (transposed) ----
    {
      const float4* a4 = (const float4*)(Arow + k0 + skq * 8);
      float4 a0 = a4[0], a1 = a4[1];
      int kb = skq * 8;
      As[kb + 0][sr] = a0.x; As[kb + 1][sr] = a0.y; As[kb + 2][sr] = a0.z; As[kb + 3][sr] = a0.w;
      As[kb + 4][sr] = a1.x; As[kb + 5][sr] = a1.y; As[kb + 6][sr] = a1.z; As[kb + 7][sr] = a1.w;
    }
    // ---- stage W (transposed) ----
    {
      const float4* w4 = (const float4*)(Wrow + k0 + skh * 16);
      float4 w0 = w4[0], w1 = w4[1], w2 = w4[2], w3 = w4[3];
      int kb = skh * 16;
      Ws[kb + 0][sc] = w0.x;  Ws[kb + 1][sc] = w0.y;  Ws[kb + 2][sc] = w0.z;  Ws[kb + 3][sc] = w0.w;
      Ws[kb + 4][sc] = w1.x;  Ws[kb + 5][sc] = w1.y;  Ws[kb + 6][sc] = w1.z;  Ws[kb + 7][sc] = w1.w;
      Ws[kb + 8][sc] = w2.x;  Ws[kb + 9][sc] = w2.y;  Ws[kb + 10][sc] = w2.z; Ws[kb + 11][sc] = w2.w;
      Ws[kb + 12][sc] = w3.x; Ws[kb + 13][sc] = w3.y; Ws[kb + 14][sc] = w3.z; Ws[kb + 15][sc] = w3.w;
    }
    __syncthreads();
    // ---- rank-1 updates ----
#pragma unroll 8
    for (int k = 0; k < 32; ++k) {
      float4 af = *(const float4*)&As[k][ty * 4];
      float4 w0 = *(const float4*)&Ws[k][tx * 8];
      float4 w1 = *(const float4*)&Ws[k][tx * 8 + 4];
      float a[4] = {af.x, af.y, af.z, af.w};
      float wv[8] = {w0.x, w0.y, w0.z, w0.w, w1.x, w1.y, w1.z, w1.w};
#pragma unroll
      for (int i = 0; i < 4; ++i)
#pragma unroll
        for (int j = 0; j < 8; ++j) acc[i][j] += a[i] * wv[j];
    }
    __syncthreads();
  }

  // ---- epilogue ----
  float4 b0 = *(const float4*)(Bb + tx * 8);
  float4 b1 = *(const float4*)(Bb + tx * 8 + 4);
  float bias[8] = {b0.x, b0.y, b0.z, b0.w, b1.x, b1.y, b1.z, b1.w};
#pragma unroll
  for (int i = 0; i < 4; ++i) {
    int v = rbase + ty * 4 + i;
    if (v < N) {
      float res[8];
      if (MODE == 0) {
#pragma unroll
        for (int j = 0; j < 8; ++j) {
          float val = acc[i][j] + bias[j];
          res[j] = val > 0.f ? val : 0.2f * val;
        }
      } else {
        float s = scale[v];
#pragma unroll
        for (int j = 0; j < 8; ++j) res[j] = acc[i][j] * s + bias[j];
      }
      float* op = out + (size_t)v * DD + tx * 8;
      *(float4*)op = make_float4(res[0], res[1], res[2], res[3]);
      *(float4*)(op + 4) = make_float4(res[4], res[5], res[6], res[7]);
    }
  }
}

extern "C" void kernel_launch(void* const* d_in, const int* in_sizes, int n_in,
                              void* d_out, int out_size, void* d_ws, size_t ws_size,
                              hipStream_t stream) {
  const float* e0 = (const float*)d_in[0];
  const float* b0 = (const float*)d_in[1];
  const float* s0 = (const float*)d_in[2];
  const float* eW = (const float*)d_in[3];
  const float* eB = (const float*)d_in[4];
  const float* bW = (const float*)d_in[5];
  const float* bB = (const float*)d_in[6];
  const float* sW = (const float*)d_in[7];
  const float* sB = (const float*)d_in[8];
  const int* src = (const int*)d_in[9];
  const int* dst = (const int*)d_in[10];
  int N = in_sizes[0] / DD;
  int E = in_sizes[9];
  int L = in_sizes[3] / (DD * DD);

  char* w = (char*)d_ws;
  int* in_deg  = (int*)w; w += (size_t)N * 4;
  int* out_deg = (int*)w; w += (size_t)N * 4;
  int* cursor  = (int*)w; w += (size_t)N * 4;
  int* row_off = (int*)w; w += (size_t)(N + 4) * 4;
  int* part    = (int*)w; w += (size_t)1024 * 4;
  int* csr_src = (int*)w; w += (size_t)E * 4;
  float* norm_in  = (float*)w; w += (size_t)N * 4;
  float* norm_out = (float*)w; w += (size_t)N * 4;
  float* inv_in   = (float*)w; w += (size_t)N * 4;
  float* sb       = (float*)w; w += (size_t)N * 4;
  float* ss       = (float*)w; w += (size_t)N * 4;
  float* buf_agg  = (float*)w; w += (size_t)N * DD * 4;
  float* buf_tan  = (float*)w; w += (size_t)N * DD * 4;

  float* oe = (float*)d_out;
  float* ob = oe + (size_t)N * DD;
  float* os = ob + (size_t)N * DD;

  int PB = (N + 255) / 256;      // scan blocks
  int AB = (N + 3) / 4;          // wave-per-row blocks
  int GB = (N + 63) / 64;        // gemm blocks (782)

  hipMemsetAsync(d_ws, 0, (size_t)3 * N * 4, stream);  // in_deg,out_deg,cursor
  degrees_kernel<<<(E + 255) / 256, 256, 0, stream>>>(src, dst, out_deg, in_deg, E);
  norms_kernel<<<(N + 255) / 256, 256, 0, stream>>>(in_deg, out_deg, norm_in, norm_out, inv_in, N);
  part_sum_kernel<<<PB, 256, 0, stream>>>(in_deg, part, N);
  part_scan_kernel<<<1, 256, 0, stream>>>(part, PB);
  local_scan_kernel<<<PB, 256, 0, stream>>>(in_deg, part, row_off, N, E);
  csr_fill_kernel<<<(E + 255) / 256, 256, 0, stream>>>(src, dst, row_off, cursor, csr_src, E);
  scale_kernel<1><<<AB, 256, 0, stream>>>(b0, sb, N);
  scale_kernel<2><<<AB, 256, 0, stream>>>(s0, ss, N);

  const float* ec = e0; const float* bc = b0; const float* scur = s0;
  for (int l = 0; l < L; ++l) {
    // Euclidean: agg (reads ec) then GEMM -> oe
    agg_euclid_kernel<<<AB, 256, 0, stream>>>(ec, row_off, csr_src, norm_out, norm_in, buf_agg, N);
    gemm_tile_kernel<0><<<GB, 256, 0, stream>>>(buf_agg, eW + (size_t)l * DD * DD, eB + (size_t)l * DD, nullptr, oe, N);
    // Hyperbolic: (logmap0-scaled) GEMM -> buf_tan, then mean-agg + expmap0 -> ob (+ next scale)
    gemm_tile_kernel<1><<<GB, 256, 0, stream>>>(bc, bW + (size_t)l * DD * DD, bB + (size_t)l * DD, sb, buf_tan, N);
    agg_mean_map_kernel<0><<<AB, 256, 0, stream>>>(buf_tan, row_off, csr_src, inv_in, ob, sb, N);
    // Spherical: (l2norm-scaled) GEMM -> buf_tan, then mean-agg + l2norm -> os (+ next scale)
    gemm_tile_kernel<2><<<GB, 256, 0, stream>>>(scur, sW + (size_t)l * DD * DD, sB + (size_t)l * DD, ss, buf_tan, N);
    agg_mean_map_kernel<1><<<AB, 256, 0, stream>>>(buf_tan, row_off, csr_src, inv_in, os, ss, N);
    ec = oe; bc = ob; scur = os;
  }
}

// Round 4
// 673.871 us; speedup vs baseline: 2.4472x; 1.2733x over previous
//
#include <hip/hip_runtime.h>
#include <hip/hip_fp16.h>
#include <math.h>

#define DD 128
// packed row: [e(128) | b(128) | s(128)] halves = 384 halves = 768 B
#define PSTRIDE 384

__device__ __forceinline__ float wave_sum_f(float x) {
#pragma unroll
  for (int m = 32; m >= 1; m >>= 1) x += __shfl_xor(x, m, 64);
  return x;
}
__device__ __forceinline__ int wave_sum_i(int x) {
#pragma unroll
  for (int m = 32; m >= 1; m >>= 1) x += __shfl_xor(x, m, 64);
  return x;
}

__global__ void degrees_kernel(const int* __restrict__ src, const int* __restrict__ dst,
                               int* __restrict__ out_deg, int* __restrict__ in_deg, int E) {
  int e = blockIdx.x * blockDim.x + threadIdx.x;
  if (e < E) {
    atomicAdd(&out_deg[src[e]], 1);
    atomicAdd(&in_deg[dst[e]], 1);
  }
}

__global__ void norms_kernel(const int* __restrict__ in_deg, const int* __restrict__ out_deg,
                             float* __restrict__ norm_in, float* __restrict__ norm_out,
                             float* __restrict__ inv_in, int N) {
  int i = blockIdx.x * blockDim.x + threadIdx.x;
  if (i < N) {
    int di = in_deg[i], dq = out_deg[i];
    norm_in[i]  = di > 0 ? 1.0f / sqrtf((float)di) : 0.0f;
    norm_out[i] = dq > 0 ? 1.0f / sqrtf((float)dq) : 0.0f;
    inv_in[i]   = di > 0 ? 1.0f / (float)di : 0.0f;
  }
}

// ---- 3-phase scan of in_deg -> row_off (exclusive) ----
__global__ void part_sum_kernel(const int* __restrict__ deg, int* __restrict__ part, int N) {
  __shared__ int wsum[4];
  int t = threadIdx.x, lane = t & 63, w = t >> 6;
  int i = blockIdx.x * 256 + t;
  int x = (i < N) ? deg[i] : 0;
  int s = wave_sum_i(x);
  if (lane == 0) wsum[w] = s;
  __syncthreads();
  if (t == 0) part[blockIdx.x] = wsum[0] + wsum[1] + wsum[2] + wsum[3];
}

__global__ void part_scan_kernel(int* __restrict__ part, int nb) {
  __shared__ int wsum[4];
  int t = threadIdx.x, lane = t & 63, w = t >> 6;
  int x = (t < nb) ? part[t] : 0;
  int v = x;
#pragma unroll
  for (int off = 1; off < 64; off <<= 1) {
    int y = __shfl_up(v, off, 64);
    if (lane >= off) v += y;
  }
  if (lane == 63) wsum[w] = v;
  __syncthreads();
  int base = 0;
  for (int q = 0; q < w; ++q) base += wsum[q];
  if (t < nb) part[t] = base + v - x;  // exclusive
}

__global__ void local_scan_kernel(const int* __restrict__ deg, const int* __restrict__ part,
                                  int* __restrict__ row_off, int N, int E) {
  __shared__ int wsum[4];
  int t = threadIdx.x, lane = t & 63, w = t >> 6;
  int i = blockIdx.x * 256 + t;
  int x = (i < N) ? deg[i] : 0;
  int v = x;
#pragma unroll
  for (int off = 1; off < 64; off <<= 1) {
    int y = __shfl_up(v, off, 64);
    if (lane >= off) v += y;
  }
  if (lane == 63) wsum[w] = v;
  __syncthreads();
  int base = 0;
  for (int q = 0; q < w; ++q) base += wsum[q];
  if (i < N) row_off[i] = part[blockIdx.x] + base + v - x;
  if (blockIdx.x == 0 && t == 0) row_off[N] = E;
}

__global__ void csr_fill_kernel(const int* __restrict__ src, const int* __restrict__ dst,
                                const int* __restrict__ row_off, int* __restrict__ cursor,
                                int* __restrict__ csr_src, int E) {
  int e = blockIdx.x * blockDim.x + threadIdx.x;
  if (e < E) {
    int d = dst[e];
    int pos = row_off[d] + atomicAdd(&cursor[d], 1);
    csr_src[pos] = src[e];
  }
}

// per-row pre-transform scalar: MODE 1 = logmap0, MODE 2 = l2norm
template <int MODE>
__global__ void scale_kernel(const float* __restrict__ x, float* __restrict__ s, int N) {
  int lane = threadIdx.x & 63;
  int v = blockIdx.x * 4 + (threadIdx.x >> 6);
  if (v >= N) return;
  float2 a = ((const float2*)x)[(size_t)v * 64 + lane];
  float n = sqrtf(wave_sum_f(a.x * a.x + a.y * a.y));
  float f;
  if (MODE == 1) {
    float nc = fminf(fmaxf(n, 1e-7f), 1.0f - 1e-5f);
    f = atanhf(nc) / fmaxf(n, 1e-7f);
  } else {
    f = 1.0f / fmaxf(n, 1e-12f);
  }
  if (lane == 0) s[v] = f;
}

// cast e0 rows into the packed half buffer (e part)
__global__ void pack_half_kernel(const float* __restrict__ x, __half* __restrict__ Pe, int N) {
  int i = blockIdx.x * 256 + threadIdx.x;  // one float2 per thread
  if (i < N * 64) {
    int v = i >> 6, l = i & 63;
    float2 a = ((const float2*)x)[i];
    ((__half2*)Pe)[(size_t)v * (PSTRIDE / 2) + l] = __floats2half2_rn(a.x, a.y);
  }
}

// Fused aggregation over packed P: one wave per dst node.
//  e: agg_e[v] = norm_in[v] * sum norm_out[s]*Pe[s]      (fp32 out, feeds e-GEMM)
//  b: ob[v] = expmap0(inv_in[v] * sum Pb[s]); sb[v] = logmap0-scale(ob[v])
//  s: os[v] = l2norm(inv_in[v] * sum Ps[s]);  ss[v] = l2-scale(os[v])
__global__ void agg_fused_kernel(const __half* __restrict__ P, const int* __restrict__ row_off,
                                 const int* __restrict__ csr_src, const float* __restrict__ norm_out,
                                 const float* __restrict__ norm_in, const float* __restrict__ inv_in,
                                 float* __restrict__ agg_e, float* __restrict__ ob,
                                 float* __restrict__ os, float* __restrict__ sb,
                                 float* __restrict__ ss, int N) {
  int lane = threadIdx.x & 63;
  int v = blockIdx.x * 4 + (threadIdx.x >> 6);
  if (v >= N) return;
  const __half2* Ph = (const __half2*)P;  // row stride 192 half2; parts at +0,+64,+128
  int beg = row_off[v], end = row_off[v + 1];
  float ex = 0.f, ey = 0.f, bx = 0.f, by = 0.f, sx = 0.f, sy = 0.f;
  int i = beg;
  for (; i + 4 <= end; i += 4) {
    int n0 = csr_src[i], n1 = csr_src[i + 1], n2 = csr_src[i + 2], n3 = csr_src[i + 3];
    size_t r0 = (size_t)n0 * 192 + lane, r1 = (size_t)n1 * 192 + lane;
    size_t r2 = (size_t)n2 * 192 + lane, r3 = (size_t)n3 * 192 + lane;
    __half2 e0 = Ph[r0], e1 = Ph[r1], e2 = Ph[r2], e3 = Ph[r3];
    __half2 b0 = Ph[r0 + 64], b1 = Ph[r1 + 64], b2 = Ph[r2 + 64], b3 = Ph[r3 + 64];
    __half2 s0 = Ph[r0 + 128], s1 = Ph[r1 + 128], s2 = Ph[r2 + 128], s3 = Ph[r3 + 128];
    float w0 = norm_out[n0], w1 = norm_out[n1], w2 = norm_out[n2], w3 = norm_out[n3];
    float2 f;
    f = __half22float2(e0); ex += f.x * w0; ey += f.y * w0;
    f = __half22float2(e1); ex += f.x * w1; ey += f.y * w1;
    f = __half22float2(e2); ex += f.x * w2; ey += f.y * w2;
    f = __half22float2(e3); ex += f.x * w3; ey += f.y * w3;
    f = __half22float2(b0); bx += f.x; by += f.y;
    f = __half22float2(b1); bx += f.x; by += f.y;
    f = __half22float2(b2); bx += f.x; by += f.y;
    f = __half22float2(b3); bx += f.x; by += f.y;
    f = __half22float2(s0); sx += f.x; sy += f.y;
    f = __half22float2(s1); sx += f.x; sy += f.y;
    f = __half22float2(s2); sx += f.x; sy += f.y;
    f = __half22float2(s3); sx += f.x; sy += f.y;
  }
  for (; i < end; ++i) {
    int n0 = csr_src[i];
    size_t r0 = (size_t)n0 * 192 + lane;
    __half2 e0 = Ph[r0], b0 = Ph[r0 + 64], s0 = Ph[r0 + 128];
    float w0 = norm_out[n0];
    float2 f;
    f = __half22float2(e0); ex += f.x * w0; ey += f.y * w0;
    f = __half22float2(b0); bx += f.x; by += f.y;
    f = __half22float2(s0); sx += f.x; sy += f.y;
  }
  // Euclid out
  float ni = norm_in[v];
  ((float2*)agg_e)[(size_t)v * 64 + lane] = make_float2(ex * ni, ey * ni);
  // b / s means
  float iv = inv_in[v];
  float ubx = bx * iv, uby = by * iv;
  float usx = sx * iv, usy = sy * iv;
  float nb = sqrtf(wave_sum_f(ubx * ubx + uby * uby));
  float ns = sqrtf(wave_sum_f(usx * usx + usy * usy));
  float fb = tanhf(nb) / fmaxf(nb, 1e-7f);          // expmap0
  float fs = 1.0f / fmaxf(ns, 1e-12f);              // l2norm
  ((float2*)ob)[(size_t)v * 64 + lane] = make_float2(ubx * fb, uby * fb);
  ((float2*)os)[(size_t)v * 64 + lane] = make_float2(usx * fs, usy * fs);
  if (lane == 0) {
    float mb = fb * nb;
    float ncb = fminf(fmaxf(mb, 1e-7f), 1.0f - 1e-5f);
    sb[v] = atanhf(ncb) / fmaxf(mb, 1e-7f);
    float ms = fs * ns;
    ss[v] = 1.0f / fmaxf(ms, 1e-12f);
  }
}

// LDS rank-1 SGEMM: res[v][c] = post( s[v]*(in[v][:] . W[c][:]) + B[c] )
// BM=64, BN=128, BK=32, 256 threads, 4x8 thread tile.
// MODE 0: s=1 + leaky_relu, writes fp32 `out` AND packed fp16 `outh`.
// MODE 1/2: s=scale[v], writes ONLY packed fp16 `outh` (consumed by agg only).
template <int MODE>
__global__ __launch_bounds__(256, 4) void gemm_tile_kernel(const float* __restrict__ in,
                                                           const float* __restrict__ W,
                                                           const float* __restrict__ Bb,
                                                           const float* __restrict__ scale,
                                                           float* __restrict__ out,
                                                           __half* __restrict__ outh, int N) {
  __shared__ float As[32][68];
  __shared__ float Ws[32][132];
  int t = threadIdx.x;
  int tx = t & 15, ty = t >> 4;
  int rbase = blockIdx.x * 64;

  float acc[4][8];
#pragma unroll
  for (int i = 0; i < 4; ++i)
#pragma unroll
    for (int j = 0; j < 8; ++j) acc[i][j] = 0.f;

  int sr = t & 63, skq = t >> 6;
  int sc = t & 127, skh = t >> 7;
  int vclamp = rbase + sr; if (vclamp >= N) vclamp = N - 1;
  const float* Arow = in + (size_t)vclamp * DD;
  const float* Wrow = W + (size_t)sc * DD;

  for (int kc = 0; kc < 4; ++kc) {
    int k0 = kc * 32;
    {
      const float4* a4 = (const float4*)(Arow + k0 + skq * 8);
      float4 a0 = a4[0], a1 = a4[1];
      int kb = skq * 8;
      As[kb + 0][sr] = a0.x; As[kb + 1][sr] = a0.y; As[kb + 2][sr] = a0.z; As[kb + 3][sr] = a0.w;
      As[kb + 4][sr] = a1.x; As[kb + 5][sr] = a1.y; As[kb + 6][sr] = a1.z; As[kb + 7][sr] = a1.w;
    }
    {
      const float4* w4 = (const float4*)(Wrow + k0 + skh * 16);
      float4 w0 = w4[0], w1 = w4[1], w2 = w4[2], w3 = w4[3];
      int kb = skh * 16;
      Ws[kb + 0][sc] = w0.x;  Ws[kb + 1][sc] = w0.y;  Ws[kb + 2][sc] = w0.z;  Ws[kb + 3][sc] = w0.w;
      Ws[kb + 4][sc] = w1.x;  Ws[kb + 5][sc] = w1.y;  Ws[kb + 6][sc] = w1.z;  Ws[kb + 7][sc] = w1.w;
      Ws[kb + 8][sc] = w2.x;  Ws[kb + 9][sc] = w2.y;  Ws[kb + 10][sc] = w2.z; Ws[kb + 11][sc] = w2.w;
      Ws[kb + 12][sc] = w3.x; Ws[kb + 13][sc] = w3.y; Ws[kb + 14][sc] = w3.z; Ws[kb + 15][sc] = w3.w;
    }
    __syncthreads();
#pragma unroll 8
    for (int k = 0; k < 32; ++k) {
      float4 af = *(const float4*)&As[k][ty * 4];
      float4 w0 = *(const float4*)&Ws[k][tx * 8];
      float4 w1 = *(const float4*)&Ws[k][tx * 8 + 4];
      float a[4] = {af.x, af.y, af.z, af.w};
      float wv[8] = {w0.x, w0.y, w0.z, w0.w, w1.x, w1.y, w1.z, w1.w};
#pragma unroll
      for (int i = 0; i < 4; ++i)
#pragma unroll
        for (int j = 0; j < 8; ++j) acc[i][j] += a[i] * wv[j];
    }
    __syncthreads();
  }

  float4 b0 = *(const float4*)(Bb + tx * 8);
  float4 b1 = *(const float4*)(Bb + tx * 8 + 4);
  float bias[8] = {b0.x, b0.y, b0.z, b0.w, b1.x, b1.y, b1.z, b1.w};
#pragma unroll
  for (int i = 0; i < 4; ++i) {
    int v = rbase + ty * 4 + i;
    if (v < N) {
      float res[8];
      if (MODE == 0) {
#pragma unroll
        for (int j = 0; j < 8; ++j) {
          float val = acc[i][j] + bias[j];
          res[j] = val > 0.f ? val : 0.2f * val;
        }
      } else {
        float s = scale[v];
#pragma unroll
        for (int j = 0; j < 8; ++j) res[j] = acc[i][j] * s + bias[j];
      }
      if (MODE == 0) {
        float* op = out + (size_t)v * DD + tx * 8;
        *(float4*)op = make_float4(res[0], res[1], res[2], res[3]);
        *(float4*)(op + 4) = make_float4(res[4], res[5], res[6], res[7]);
      }
      __half2* q = (__half2*)(outh + (size_t)v * PSTRIDE + tx * 8);
      q[0] = __floats2half2_rn(res[0], res[1]);
      q[1] = __floats2half2_rn(res[2], res[3]);
      q[2] = __floats2half2_rn(res[4], res[5]);
      q[3] = __floats2half2_rn(res[6], res[7]);
    }
  }
}

extern "C" void kernel_launch(void* const* d_in, const int* in_sizes, int n_in,
                              void* d_out, int out_size, void* d_ws, size_t ws_size,
                              hipStream_t stream) {
  const float* e0 = (const float*)d_in[0];
  const float* b0 = (const float*)d_in[1];
  const float* s0 = (const float*)d_in[2];
  const float* eW = (const float*)d_in[3];
  const float* eB = (const float*)d_in[4];
  const float* bW = (const float*)d_in[5];
  const float* bB = (const float*)d_in[6];
  const float* sW = (const float*)d_in[7];
  const float* sB = (const float*)d_in[8];
  const int* src = (const int*)d_in[9];
  const int* dst = (const int*)d_in[10];
  int N = in_sizes[0] / DD;
  int E = in_sizes[9];
  int L = in_sizes[3] / (DD * DD);

  char* w = (char*)d_ws;
  int* in_deg  = (int*)w; w += (size_t)N * 4;
  int* out_deg = (int*)w; w += (size_t)N * 4;
  int* cursor  = (int*)w; w += (size_t)N * 4;
  int* row_off = (int*)w; w += (size_t)(N + 4) * 4;
  int* part    = (int*)w; w += (size_t)1024 * 4;
  int* csr_src = (int*)w; w += (size_t)E * 4;
  float* norm_in  = (float*)w; w += (size_t)N * 4;
  float* norm_out = (float*)w; w += (size_t)N * 4;
  float* inv_in   = (float*)w; w += (size_t)N * 4;
  float* sb       = (float*)w; w += (size_t)N * 4;
  float* ss       = (float*)w; w += (size_t)N * 4;
  float* buf_agg  = (float*)w; w += (size_t)N * DD * 4;
  __half* P       = (__half*)w; w += (size_t)N * PSTRIDE * 2;

  float* oe = (float*)d_out;
  float* ob = oe + (size_t)N * DD;
  float* os = ob + (size_t)N * DD;

  int PB = (N + 255) / 256;
  int AB = (N + 3) / 4;
  int GB = (N + 63) / 64;
  int KB = (N * 64 + 255) / 256;

  hipMemsetAsync(d_ws, 0, (size_t)3 * N * 4, stream);  // in_deg,out_deg,cursor
  degrees_kernel<<<(E + 255) / 256, 256, 0, stream>>>(src, dst, out_deg, in_deg, E);
  norms_kernel<<<(N + 255) / 256, 256, 0, stream>>>(in_deg, out_deg, norm_in, norm_out, inv_in, N);
  part_sum_kernel<<<PB, 256, 0, stream>>>(in_deg, part, N);
  part_scan_kernel<<<1, 256, 0, stream>>>(part, PB);
  local_scan_kernel<<<PB, 256, 0, stream>>>(in_deg, part, row_off, N, E);
  csr_fill_kernel<<<(E + 255) / 256, 256, 0, stream>>>(src, dst, row_off, cursor, csr_src, E);
  scale_kernel<1><<<AB, 256, 0, stream>>>(b0, sb, N);
  scale_kernel<2><<<AB, 256, 0, stream>>>(s0, ss, N);
  pack_half_kernel<<<KB, 256, 0, stream>>>(e0, P, N);

  const float* bc = b0; const float* scur = s0;
  for (int l = 0; l < L; ++l) {
    // b/s GEMMs write packed fp16 tan rows
    gemm_tile_kernel<1><<<GB, 256, 0, stream>>>(bc, bW + (size_t)l * DD * DD, bB + (size_t)l * DD, sb, nullptr, P + 128, N);
    gemm_tile_kernel<2><<<GB, 256, 0, stream>>>(scur, sW + (size_t)l * DD * DD, sB + (size_t)l * DD, ss, nullptr, P + 256, N);
    // one fused gather for all three branches
    agg_fused_kernel<<<AB, 256, 0, stream>>>(P, row_off, csr_src, norm_out, norm_in, inv_in,
                                             buf_agg, ob, os, sb, ss, N);
    // e-GEMM: fp32 output + fp16 pack for next layer's gather
    gemm_tile_kernel<0><<<GB, 256, 0, stream>>>(buf_agg, eW + (size_t)l * DD * DD, eB + (size_t)l * DD, nullptr, oe, P, N);
    bc = ob; scur = os;
  }
}

// Round 5
// 588.239 us; speedup vs baseline: 2.8035x; 1.1456x over previous
//
#include <hip/hip_runtime.h>
#include <math.h>

#define DD 128
// packed row: [e(128) | b(128) | s(128)] fp16 = 768 B
#define PSTRIDE 384

typedef _Float16 half8 __attribute__((ext_vector_type(8)));
typedef _Float16 half2v __attribute__((ext_vector_type(2)));
typedef float floatx4 __attribute__((ext_vector_type(4)));

__device__ __forceinline__ float wave_sum_f(float x) {
#pragma unroll
  for (int m = 32; m >= 1; m >>= 1) x += __shfl_xor(x, m, 64);
  return x;
}
__device__ __forceinline__ int wave_sum_i(int x) {
#pragma unroll
  for (int m = 32; m >= 1; m >>= 1) x += __shfl_xor(x, m, 64);
  return x;
}

__global__ void degrees_kernel(const int* __restrict__ src, const int* __restrict__ dst,
                               int* __restrict__ out_deg, int* __restrict__ in_deg, int E) {
  int e = blockIdx.x * blockDim.x + threadIdx.x;
  if (e < E) {
    atomicAdd(&out_deg[src[e]], 1);
    atomicAdd(&in_deg[dst[e]], 1);
  }
}

__global__ void norms_kernel(const int* __restrict__ in_deg, const int* __restrict__ out_deg,
                             float* __restrict__ norm_in, float* __restrict__ norm_out,
                             float* __restrict__ inv_in, int N) {
  int i = blockIdx.x * blockDim.x + threadIdx.x;
  if (i < N) {
    int di = in_deg[i], dq = out_deg[i];
    norm_in[i]  = di > 0 ? 1.0f / sqrtf((float)di) : 0.0f;
    norm_out[i] = dq > 0 ? 1.0f / sqrtf((float)dq) : 0.0f;
    inv_in[i]   = di > 0 ? 1.0f / (float)di : 0.0f;
  }
}

// ---- 3-phase scan of in_deg -> row_off (exclusive) ----
__global__ void part_sum_kernel(const int* __restrict__ deg, int* __restrict__ part, int N) {
  __shared__ int wsum[4];
  int t = threadIdx.x, lane = t & 63, w = t >> 6;
  int i = blockIdx.x * 256 + t;
  int x = (i < N) ? deg[i] : 0;
  int s = wave_sum_i(x);
  if (lane == 0) wsum[w] = s;
  __syncthreads();
  if (t == 0) part[blockIdx.x] = wsum[0] + wsum[1] + wsum[2] + wsum[3];
}

__global__ void part_scan_kernel(int* __restrict__ part, int nb) {
  __shared__ int wsum[4];
  int t = threadIdx.x, lane = t & 63, w = t >> 6;
  int x = (t < nb) ? part[t] : 0;
  int v = x;
#pragma unroll
  for (int off = 1; off < 64; off <<= 1) {
    int y = __shfl_up(v, off, 64);
    if (lane >= off) v += y;
  }
  if (lane == 63) wsum[w] = v;
  __syncthreads();
  int base = 0;
  for (int q = 0; q < w; ++q) base += wsum[q];
  if (t < nb) part[t] = base + v - x;  // exclusive
}

__global__ void local_scan_kernel(const int* __restrict__ deg, const int* __restrict__ part,
                                  int* __restrict__ row_off, int N, int E) {
  __shared__ int wsum[4];
  int t = threadIdx.x, lane = t & 63, w = t >> 6;
  int i = blockIdx.x * 256 + t;
  int x = (i < N) ? deg[i] : 0;
  int v = x;
#pragma unroll
  for (int off = 1; off < 64; off <<= 1) {
    int y = __shfl_up(v, off, 64);
    if (lane >= off) v += y;
  }
  if (lane == 63) wsum[w] = v;
  __syncthreads();
  int base = 0;
  for (int q = 0; q < w; ++q) base += wsum[q];
  if (i < N) row_off[i] = part[blockIdx.x] + base + v - x;
  if (blockIdx.x == 0 && t == 0) row_off[N] = E;
}

__global__ void csr_fill_kernel(const int* __restrict__ src, const int* __restrict__ dst,
                                const int* __restrict__ row_off, int* __restrict__ cursor,
                                int* __restrict__ csr_src, int E) {
  int e = blockIdx.x * blockDim.x + threadIdx.x;
  if (e < E) {
    int d = dst[e];
    int pos = row_off[d] + atomicAdd(&cursor[d], 1);
    csr_src[pos] = src[e];
  }
}

// per-row pre-transform scalar: MODE 1 = logmap0, MODE 2 = l2norm
template <int MODE>
__global__ void scale_kernel(const float* __restrict__ x, float* __restrict__ s, int N) {
  int lane = threadIdx.x & 63;
  int v = blockIdx.x * 4 + (threadIdx.x >> 6);
  if (v >= N) return;
  float2 a = ((const float2*)x)[(size_t)v * 64 + lane];
  float n = sqrtf(wave_sum_f(a.x * a.x + a.y * a.y));
  float f;
  if (MODE == 1) {
    float nc = fminf(fmaxf(n, 1e-7f), 1.0f - 1e-5f);
    f = atanhf(nc) / fmaxf(n, 1e-7f);
  } else {
    f = 1.0f / fmaxf(n, 1e-12f);
  }
  if (lane == 0) s[v] = f;
}

// fp32 -> fp16 bulk convert (for W matrices)
__global__ void wcvt_kernel(const float* __restrict__ Wf, _Float16* __restrict__ Wh, int n) {
  int i = blockIdx.x * 256 + threadIdx.x;
  if (i < n) Wh[i] = (_Float16)Wf[i];
}

// cast fp32 rows into one part of the packed half buffer
__global__ void pack_half_kernel(const float* __restrict__ x, _Float16* __restrict__ Pp, int N) {
  int i = blockIdx.x * 256 + threadIdx.x;  // one float2 per thread
  if (i < N * 64) {
    int v = i >> 6, l = i & 63;
    float2 a = ((const float2*)x)[i];
    half2v h; h.x = (_Float16)a.x; h.y = (_Float16)a.y;
    *(half2v*)&Pp[(size_t)v * PSTRIDE + l * 2] = h;
  }
}

// MFMA fp16 GEMM: t[v][c] = post( in[v][:] . W[c][:] )
// MODE 0: post = identity (e-branch; bias/norm applied in gather)
// MODE 1: post = scale[v]*acc + Bb[c]   (b/s tangent branches)
// Block: 64 rows x 128 cols, K=128 fully staged in LDS, one barrier.
// Wave w owns cols [32w,32w+32): B-frags register-cached (8 x half8).
template <int MODE>
__global__ __launch_bounds__(256) void gemm_mfma_kernel(const _Float16* __restrict__ Ain,  // stride PSTRIDE
                                                        const _Float16* __restrict__ Wh,   // 128x128 row-major
                                                        const float* __restrict__ Bb,
                                                        const float* __restrict__ scale,
                                                        _Float16* __restrict__ Qout,       // stride PSTRIDE
                                                        int N) {
  __shared__ _Float16 As[64 * 136];
  __shared__ _Float16 Ws[128 * 136];
  int t = threadIdx.x;
  int rbase = blockIdx.x * 64;

  // stage W (fp16, pad 136 to break power-of-2 bank stride)
#pragma unroll
  for (int i = 0; i < 8; ++i) {
    int idx = i * 256 + t;                 // 16B chunk id
    int row = idx >> 4, col = (idx & 15) * 8;
    *(half8*)&Ws[row * 136 + col] = *(const half8*)&Wh[idx * 8];
  }
  // stage A: 4 threads per row, 32 halves each
  {
    int ar = t >> 2, aseg = t & 3;
    int av = rbase + ar; if (av >= N) av = N - 1;
    const _Float16* Ap = Ain + (size_t)av * PSTRIDE + aseg * 32;
    _Float16* Ad = &As[ar * 136 + aseg * 32];
    *(half8*)&Ad[0]  = *(const half8*)&Ap[0];
    *(half8*)&Ad[8]  = *(const half8*)&Ap[8];
    *(half8*)&Ad[16] = *(const half8*)&Ap[16];
    *(half8*)&Ad[24] = *(const half8*)&Ap[24];
  }
  __syncthreads();

  int lane = t & 63, w = t >> 6;
  int m = lane & 15, quad = lane >> 4;
  int c0 = w * 32;

  // B-frags: lane holds W[c0+16*tj+m][kk*32+quad*8 .. +7]
  half8 bf[2][4];
#pragma unroll
  for (int tj = 0; tj < 2; ++tj)
#pragma unroll
    for (int kk = 0; kk < 4; ++kk)
      bf[tj][kk] = *(const half8*)&Ws[(c0 + tj * 16 + m) * 136 + kk * 32 + quad * 8];

  float bias0 = 0.f, bias1 = 0.f;
  if (MODE) { bias0 = Bb[c0 + m]; bias1 = Bb[c0 + 16 + m]; }

#pragma unroll
  for (int r = 0; r < 4; ++r) {
    int row0 = r * 16;
    floatx4 acc0 = {0.f, 0.f, 0.f, 0.f}, acc1 = {0.f, 0.f, 0.f, 0.f};
#pragma unroll
    for (int kk = 0; kk < 4; ++kk) {
      half8 af = *(const half8*)&As[(row0 + m) * 136 + kk * 32 + quad * 8];
      acc0 = __builtin_amdgcn_mfma_f32_16x16x32_f16(af, bf[0][kk], acc0, 0, 0, 0);
      acc1 = __builtin_amdgcn_mfma_f32_16x16x32_f16(af, bf[1][kk], acc1, 0, 0, 0);
    }
    // C/D layout: col = lane&15, row = quad*4 + reg
    int vrow = rbase + row0 + quad * 4;
#pragma unroll
    for (int reg = 0; reg < 4; ++reg) {
      int v = vrow + reg;
      if (v < N) {
        float x0 = acc0[reg], x1 = acc1[reg];
        if (MODE) { float s = scale[v]; x0 = x0 * s + bias0; x1 = x1 * s + bias1; }
        Qout[(size_t)v * PSTRIDE + c0 + m]      = (_Float16)x0;
        Qout[(size_t)v * PSTRIDE + c0 + 16 + m] = (_Float16)x1;
      }
    }
  }
}

// Fused gather over packed Q (one wave per dst node):
//  e: oe[v] = leaky( norm_in[v]*sum norm_out[s]*Qe[s] + eB )  -> fp32 (+fp16 pack)
//  b: ob[v] = expmap0(inv_in[v]*sum Qb[s]) -> fp32 (+pack), sb[v] = next logmap scale
//  s: os[v] = l2norm(inv_in[v]*sum Qs[s])  -> fp32 (+pack), ss[v] = next l2 scale
__global__ void agg_fused_kernel(const _Float16* __restrict__ Q, const int* __restrict__ row_off,
                                 const int* __restrict__ csr_src, const float* __restrict__ norm_out,
                                 const float* __restrict__ norm_in, const float* __restrict__ inv_in,
                                 const float* __restrict__ eBias,
                                 float* __restrict__ oe, float* __restrict__ ob,
                                 float* __restrict__ os, _Float16* __restrict__ Pnext,
                                 float* __restrict__ sb, float* __restrict__ ss,
                                 int N, int write_pack) {
  int lane = threadIdx.x & 63;
  int v = blockIdx.x * 4 + (threadIdx.x >> 6);
  if (v >= N) return;
  const half2v* Ph = (const half2v*)Q;  // row stride 192 half2; parts at +0,+64,+128
  int beg = row_off[v], end = row_off[v + 1];
  float ex = 0.f, ey = 0.f, bx = 0.f, by = 0.f, sx = 0.f, sy = 0.f;
  int i = beg;
  for (; i + 4 <= end; i += 4) {
    int n0 = csr_src[i], n1 = csr_src[i + 1], n2 = csr_src[i + 2], n3 = csr_src[i + 3];
    size_t r0 = (size_t)n0 * 192 + lane, r1 = (size_t)n1 * 192 + lane;
    size_t r2 = (size_t)n2 * 192 + lane, r3 = (size_t)n3 * 192 + lane;
    half2v e0 = Ph[r0], e1 = Ph[r1], e2 = Ph[r2], e3 = Ph[r3];
    half2v b0 = Ph[r0 + 64], b1 = Ph[r1 + 64], b2 = Ph[r2 + 64], b3 = Ph[r3 + 64];
    half2v s0 = Ph[r0 + 128], s1 = Ph[r1 + 128], s2 = Ph[r2 + 128], s3 = Ph[r3 + 128];
    float w0 = norm_out[n0], w1 = norm_out[n1], w2 = norm_out[n2], w3 = norm_out[n3];
    ex += (float)e0.x * w0 + (float)e1.x * w1 + (float)e2.x * w2 + (float)e3.x * w3;
    ey += (float)e0.y * w0 + (float)e1.y * w1 + (float)e2.y * w2 + (float)e3.y * w3;
    bx += (float)b0.x + (float)b1.x + (float)b2.x + (float)b3.x;
    by += (float)b0.y + (float)b1.y + (float)b2.y + (float)b3.y;
    sx += (float)s0.x + (float)s1.x + (float)s2.x + (float)s3.x;
    sy += (float)s0.y + (float)s1.y + (float)s2.y + (float)s3.y;
  }
  for (; i < end; ++i) {
    int n0 = csr_src[i];
    size_t r0 = (size_t)n0 * 192 + lane;
    half2v e0 = Ph[r0], b0 = Ph[r0 + 64], s0 = Ph[r0 + 128];
    float w0 = norm_out[n0];
    ex += (float)e0.x * w0; ey += (float)e0.y * w0;
    bx += (float)b0.x; by += (float)b0.y;
    sx += (float)s0.x; sy += (float)s0.y;
  }
  // ---- e epilogue: bias + leaky ----
  float ni = norm_in[v];
  float2 eb = ((const float2*)eBias)[lane];
  float h0 = ex * ni + eb.x, h1 = ey * ni + eb.y;
  h0 = h0 > 0.f ? h0 : 0.2f * h0;
  h1 = h1 > 0.f ? h1 : 0.2f * h1;
  ((float2*)oe)[(size_t)v * 64 + lane] = make_float2(h0, h1);
  // ---- b / s means + maps ----
  float iv = inv_in[v];
  float ubx = bx * iv, uby = by * iv;
  float usx = sx * iv, usy = sy * iv;
  float nb = sqrtf(wave_sum_f(ubx * ubx + uby * uby));
  float ns = sqrtf(wave_sum_f(usx * usx + usy * usy));
  float fb = tanhf(nb) / fmaxf(nb, 1e-7f);          // expmap0
  float fs = 1.0f / fmaxf(ns, 1e-12f);              // l2norm
  float ob0 = ubx * fb, ob1 = uby * fb;
  float os0 = usx * fs, os1 = usy * fs;
  ((float2*)ob)[(size_t)v * 64 + lane] = make_float2(ob0, ob1);
  ((float2*)os)[(size_t)v * 64 + lane] = make_float2(os0, os1);
  if (write_pack) {
    _Float16* Pr = Pnext + (size_t)v * PSTRIDE + lane * 2;
    half2v he; he.x = (_Float16)h0;  he.y = (_Float16)h1;
    half2v hb; hb.x = (_Float16)ob0; hb.y = (_Float16)ob1;
    half2v hs; hs.x = (_Float16)os0; hs.y = (_Float16)os1;
    *(half2v*)&Pr[0]   = he;
    *(half2v*)&Pr[128] = hb;
    *(half2v*)&Pr[256] = hs;
  }
  if (lane == 0) {
    float mb = fb * nb;
    float ncb = fminf(fmaxf(mb, 1e-7f), 1.0f - 1e-5f);
    sb[v] = atanhf(ncb) / fmaxf(mb, 1e-7f);
    float ms = fs * ns;
    ss[v] = 1.0f / fmaxf(ms, 1e-12f);
  }
}

extern "C" void kernel_launch(void* const* d_in, const int* in_sizes, int n_in,
                              void* d_out, int out_size, void* d_ws, size_t ws_size,
                              hipStream_t stream) {
  const float* e0 = (const float*)d_in[0];
  const float* b0 = (const float*)d_in[1];
  const float* s0 = (const float*)d_in[2];
  const float* eW = (const float*)d_in[3];
  const float* eB = (const float*)d_in[4];
  const float* bW = (const float*)d_in[5];
  const float* bB = (const float*)d_in[6];
  const float* sW = (const float*)d_in[7];
  const float* sB = (const float*)d_in[8];
  const int* src = (const int*)d_in[9];
  const int* dst = (const int*)d_in[10];
  int N = in_sizes[0] / DD;
  int E = in_sizes[9];
  int L = in_sizes[3] / (DD * DD);

  char* w = (char*)d_ws;
  int* in_deg  = (int*)w; w += (size_t)N * 4;
  int* out_deg = (int*)w; w += (size_t)N * 4;
  int* cursor  = (int*)w; w += (size_t)N * 4;
  int* row_off = (int*)w; w += (size_t)(N + 4) * 4;
  int* part    = (int*)w; w += (size_t)1024 * 4;
  int* csr_src = (int*)w; w += (size_t)E * 4;
  float* norm_in  = (float*)w; w += (size_t)N * 4;
  float* norm_out = (float*)w; w += (size_t)N * 4;
  float* inv_in   = (float*)w; w += (size_t)N * 4;
  float* sb       = (float*)w; w += (size_t)N * 4;
  float* ss       = (float*)w; w += (size_t)N * 4;
  _Float16* P     = (_Float16*)w; w += (size_t)N * PSTRIDE * 2;
  _Float16* Q     = (_Float16*)w; w += (size_t)N * PSTRIDE * 2;
  _Float16* whE   = (_Float16*)w; w += (size_t)L * DD * DD * 2;
  _Float16* whB   = (_Float16*)w; w += (size_t)L * DD * DD * 2;
  _Float16* whS   = (_Float16*)w; w += (size_t)L * DD * DD * 2;

  float* oe = (float*)d_out;
  float* ob = oe + (size_t)N * DD;
  float* os = ob + (size_t)N * DD;

  int PB = (N + 255) / 256;
  int AB = (N + 3) / 4;
  int GB = (N + 63) / 64;
  int KB = (N * 64 + 255) / 256;
  int WB = (L * DD * DD + 255) / 256;

  hipMemsetAsync(d_ws, 0, (size_t)3 * N * 4, stream);  // in_deg,out_deg,cursor
  degrees_kernel<<<(E + 255) / 256, 256, 0, stream>>>(src, dst, out_deg, in_deg, E);
  norms_kernel<<<(N + 255) / 256, 256, 0, stream>>>(in_deg, out_deg, norm_in, norm_out, inv_in, N);
  part_sum_kernel<<<PB, 256, 0, stream>>>(in_deg, part, N);
  part_scan_kernel<<<1, 256, 0, stream>>>(part, PB);
  local_scan_kernel<<<PB, 256, 0, stream>>>(in_deg, part, row_off, N, E);
  csr_fill_kernel<<<(E + 255) / 256, 256, 0, stream>>>(src, dst, row_off, cursor, csr_src, E);
  scale_kernel<1><<<AB, 256, 0, stream>>>(b0, sb, N);
  scale_kernel<2><<<AB, 256, 0, stream>>>(s0, ss, N);
  wcvt_kernel<<<WB, 256, 0, stream>>>(eW, whE, L * DD * DD);
  wcvt_kernel<<<WB, 256, 0, stream>>>(bW, whB, L * DD * DD);
  wcvt_kernel<<<WB, 256, 0, stream>>>(sW, whS, L * DD * DD);
  pack_half_kernel<<<KB, 256, 0, stream>>>(e0, P, N);
  pack_half_kernel<<<KB, 256, 0, stream>>>(b0, P + 128, N);
  pack_half_kernel<<<KB, 256, 0, stream>>>(s0, P + 256, N);

  for (int l = 0; l < L; ++l) {
    gemm_mfma_kernel<0><<<GB, 256, 0, stream>>>(P, whE + (size_t)l * DD * DD, nullptr, nullptr, Q, N);
    gemm_mfma_kernel<1><<<GB, 256, 0, stream>>>(P + 128, whB + (size_t)l * DD * DD, bB + (size_t)l * DD, sb, Q + 128, N);
    gemm_mfma_kernel<1><<<GB, 256, 0, stream>>>(P + 256, whS + (size_t)l * DD * DD, sB + (size_t)l * DD, ss, Q + 256, N);
    agg_fused_kernel<<<AB, 256, 0, stream>>>(Q, row_off, csr_src, norm_out, norm_in, inv_in,
                                             eB + (size_t)l * DD, oe, ob, os, P, sb, ss, N,
                                             (l < L - 1) ? 1 : 0);
  }
}